// Round 13
// baseline (86.986 us; speedup 1.0000x reference)
//
#include <hip/hip_runtime.h>

// Problem geometry: B=8, H=512, W=512, HID=64, T=16.
#define HH 512
#define WW 512
#define WPR 16                    // u32 words per full-width row
#define NSTEP 15                  // temporal depth (T-1)
#define TROWS 32                  // per-wave tile rows = RO(2) + 2*NSTEP
// Trapezoid exactness (RO=2, full width): valid rows after step s are
// [s, 32-s). Step s computes pairs l = s+2*pr, pr<16-s (rows [s, 32-s)),
// reading rows [s-1, 32-s] which is exactly the previous valid set. Owned
// rows are tile rows 15,16 = the final valid pair at s=15.

// Per-wave LDS ordering only — NO block barrier in the loop.
#define WAIT_LGKM() do {                                      \
    asm volatile("s_waitcnt lgkmcnt(0)" ::: "memory");        \
    __builtin_amdgcn_sched_barrier(0);                        \
} while (0)

// ---------------------------------------------------------------------------
// Kernel 1 (R10-verbatim, verified absmax 0): out[0]=f0; bit-pack field;
// blocks 0..63 build the 64K-entry quad-LUT (4-bit col-windows of 4 rows ->
// 4 result bits = cells (2j,2j+1) of rows l, l+1), 8 entries per u32, 32 KiB.
// ---------------------------------------------------------------------------
__global__ __launch_bounds__(512) void init_pack(const float* __restrict__ f0,
                                                 const float* __restrict__ W1,
                                                 const float* __restrict__ b1,
                                                 const float* __restrict__ W2,
                                                 const float* __restrict__ b2,
                                                 int hid,
                                                 float* __restrict__ out,
                                                 unsigned long long* __restrict__ field,
                                                 unsigned int* __restrict__ lut16g) {
    __shared__ unsigned int rule[512];
    const int tid = threadIdx.x;
    int c = blockIdx.x * 512 + tid;
    float v = f0[c];
    out[c] = v;
    unsigned long long m = __ballot(v > 0.5f);
    if ((tid & 63) == 0) field[c >> 6] = m;

    if (blockIdx.x < 64) {
        {   // rule table — byte-identical math to the verified build.
            int p = tid;  // 0..511
            float logit = b2[0];
            for (int k = 0; k < hid; ++k) {
                float a = b1[k];
#pragma unroll
                for (int nn = 0; nn < 9; ++nn)
                    if (p & (1 << nn)) a += W1[nn * hid + k];
                logit += fmaxf(a, 0.0f) * W2[k];
            }
            rule[p] = (logit > 0.0f) ? 1u : 0u;
        }
        __syncthreads();
        if (tid < 128) {   // this block's 128-word slice of the quad-LUT
            int word = blockIdx.x * 128 + tid;
            unsigned int wv = 0;
#pragma unroll
            for (int k = 0; k < 8; ++k) {
                unsigned int e = (unsigned int)word * 8u + k;
                unsigned int a = e & 15u, b = (e >> 4) & 15u;
                unsigned int cc = (e >> 8) & 15u, d = (e >> 12) & 15u;
                unsigned int bit0 = rule[(a & 7u) | ((b & 7u) << 3) | ((cc & 7u) << 6)];
                unsigned int bit1 = rule[((a >> 1) & 7u) | (((b >> 1) & 7u) << 3) | (((cc >> 1) & 7u) << 6)];
                unsigned int bit2 = rule[(b & 7u) | ((cc & 7u) << 3) | ((d & 7u) << 6)];
                unsigned int bit3 = rule[((b >> 1) & 7u) | (((cc >> 1) & 7u) << 3) | (((d >> 1) & 7u) << 6)];
                wv |= (bit0 | (bit1 << 1) | (bit2 << 2) | (bit3 << 3)) << (4 * k);
            }
            lut16g[word] = wv;
        }
    }
}

// ---------------------------------------------------------------------------
// Kernel 2 "mega": wave-autonomous. 512 blocks (8 images x 64 row-groups) x
// 256 thr = 4 waves; each wave owns 2 output rows and a private 32-row x
// 16-word double-buffered LDS tile (4 KiB). ONE __syncthreads total (after
// the cooperative 32 KiB quad-LUT load); the 15-step loop has NO barriers —
// per-wave lgkmcnt ordering only. Emit (4 float4/lane/step) streams freely.
// ---------------------------------------------------------------------------
__global__ __launch_bounds__(256) void mega(const unsigned int* __restrict__ field,
                                            const unsigned int* __restrict__ lut16g,
                                            float* __restrict__ out, int n) {
    __shared__ alignas(16) unsigned int lut16[8192];      // 32 KiB
    __shared__ unsigned int tiles[4][2][TROWS * WPR];     // 16 KiB

    const int tid  = threadIdx.x;
    const int wv   = tid >> 6;
    const int lane = tid & 63;
    const int rg = blockIdx.x & 63;
    const int b  = blockIdx.x >> 6;
    const int gr0 = rg * 8 + wv * 2;      // first owned global row of wave

    // cooperative quad-LUT load (R10-verbatim pattern), the only barrier.
    for (int i = tid; i < 2048; i += 256)
        ((uint4*)lut16)[i] = ((const uint4*)lut16g)[i];
    __syncthreads();

    unsigned int* oldb = &tiles[wv][0][0];
    unsigned int* newb = &tiles[wv][1][0];

    // per-wave tile load: rows gr0-15 .. gr0+16 (wrap &511), full width.
    {
        const unsigned int* F = field + b * (HH * WPR);
        for (int i = lane; i < TROWS * WPR; i += 64) {
            int l = i >> 4, w = i & 15;
            int g = (gr0 - NSTEP + l) & (HH - 1);
            oldb[i] = F[g * WPR + w];
        }
    }
    WAIT_LGKM();

    float* outb = out + (size_t)b * (HH * WW);

    for (int s = 1; s <= NSTEP; ++s) {
        // compute pairs: rows [s, 32-s), (16-s)*16 word-tasks, per-wave.
        const int ntask = (16 - s) * WPR;
        for (int task = lane; task < ntask; task += 64) {
            const int pr = task >> 4;
            const int w  = task & 15;
            const int l  = s + 2 * pr;
            const unsigned int* Ra = oldb + (l - 1) * WPR;
            const unsigned int* Rb = oldb + l * WPR;
            const unsigned int* Rc = oldb + (l + 1) * WPR;
            const unsigned int* Rd = oldb + (l + 2) * WPR;
            const int wl = (w + 15) & 15, wn = (w + 1) & 15;   // full-width wrap
            unsigned long long ea = ((((unsigned long long)Ra[wn] << 32) | Ra[w]) << 1) | (Ra[wl] >> 31);
            unsigned long long eb = ((((unsigned long long)Rb[wn] << 32) | Rb[w]) << 1) | (Rb[wl] >> 31);
            unsigned long long ec = ((((unsigned long long)Rc[wn] << 32) | Rc[w]) << 1) | (Rc[wl] >> 31);
            unsigned long long ed = ((((unsigned long long)Rd[wn] << 32) | Rd[w]) << 1) | (Rd[wl] >> 31);
            unsigned int owb = 0, owc = 0;
#pragma unroll
            for (int j = 0; j < 16; ++j) {
                unsigned int idx = (unsigned int)((ea >> (2 * j)) & 15ull)
                                 | ((unsigned int)((eb >> (2 * j)) & 15ull) << 4)
                                 | ((unsigned int)((ec >> (2 * j)) & 15ull) << 8)
                                 | ((unsigned int)((ed >> (2 * j)) & 15ull) << 12);
                unsigned int ent = (lut16[idx >> 3] >> ((idx & 7u) * 4)) & 15u;
                owb |= (ent & 3u) << (2 * j);
                owc |= ((ent >> 2) & 3u) << (2 * j);
            }
            newb[l * WPR + w] = owb;
            newb[(l + 1) * WPR + w] = owc;
        }
        WAIT_LGKM();   // own writes/reads retired; no cross-wave dependency.

        // emit step s: owned rows = tile rows 15,16 -> 4 x 1KiB float4 passes.
        float* outt = outb + (size_t)s * n;
#pragma unroll
        for (int p = 0; p < 4; ++p) {
            int row = NSTEP + (p >> 1);               // tile row 15 or 16
            int col = (p & 1) * 256 + lane * 4;
            unsigned int wd = newb[row * WPR + (col >> 5)];
            unsigned int nib = (wd >> (col & 31)) & 15u;
            float4 v;
            v.x = (float)(nib & 1u);
            v.y = (float)((nib >> 1) & 1u);
            v.z = (float)((nib >> 2) & 1u);
            v.w = (float)(nib >> 3);
            *(float4*)(outt + (size_t)(gr0 + (p >> 1)) * WW + col) = v;
        }
        unsigned int* tmp = oldb; oldb = newb; newb = tmp;
    }
}

// ---------------------------------------------------------------------------
// Launch: init_pack -> mega (2 dispatches).
// d_ws: [0, 32768)            quad-LUT (8192 u32)
//       [32768, 32768 + n/8)  packed step-0 bit field (256 KiB)
// ---------------------------------------------------------------------------
extern "C" void kernel_launch(void* const* d_in, const int* in_sizes, int n_in,
                              void* d_out, int out_size, void* d_ws, size_t ws_size,
                              hipStream_t stream) {
    const float* f0 = (const float*)d_in[0];
    const float* W1 = (const float*)d_in[1];
    const float* b1 = (const float*)d_in[2];
    const float* W2 = (const float*)d_in[3];
    const float* b2 = (const float*)d_in[4];
    float* out = (float*)d_out;

    const int n = in_sizes[0];        // B*1*H*W = 2,097,152
    const int hid = in_sizes[2];      // 64

    char* ws = (char*)d_ws;
    unsigned int* lut16g = (unsigned int*)ws;
    unsigned long long* fld = (unsigned long long*)(ws + 32768);

    init_pack<<<n / 512, 512, 0, stream>>>(f0, W1, b1, W2, b2, hid, out, fld, lut16g);
    mega<<<512, 256, 0, stream>>>((const unsigned int*)fld, lut16g, out, n);
}

// Round 14
// 77.619 us; speedup vs baseline: 1.1207x; 1.1207x over previous
//
#include <hip/hip_runtime.h>

// Problem geometry: B=8, H=512, W=512, HID=64, T=16.
#define HH 512
#define WW 512
#define WPR 16                    // u32 words per full-width row
#define RO 8                      // owned rows per block
#define HALO 15                   // T-1 steps of temporal blocking
#define ROWS (RO + 2 * HALO)      // 38 tile rows
#define NSTEP 15

// lgkm-only barrier (verified rounds 7/8/10/11): waits only on LDS ops;
// global float stores stay in flight across steps.
#define STEP_BARRIER() do {                                   \
    asm volatile("s_waitcnt lgkmcnt(0)" ::: "memory");        \
    __builtin_amdgcn_s_barrier();                             \
    __builtin_amdgcn_sched_barrier(0);                        \
} while (0)

// ---------------------------------------------------------------------------
// Kernel 1 (R10-verbatim, verified absmax 0): out[0]=f0; bit-pack field;
// blocks 0..63 build the 64K-entry quad-LUT (idx16 = 4-bit col-windows of
// rows l-1,l,l+1,l+2 -> 4 bits: cells (2j,2j+1) of rows l and l+1), 8 entries
// per u32, 32 KiB total.
// ---------------------------------------------------------------------------
__global__ __launch_bounds__(512) void init_pack(const float* __restrict__ f0,
                                                 const float* __restrict__ W1,
                                                 const float* __restrict__ b1,
                                                 const float* __restrict__ W2,
                                                 const float* __restrict__ b2,
                                                 int hid,
                                                 float* __restrict__ out,
                                                 unsigned long long* __restrict__ field,
                                                 unsigned int* __restrict__ lut16g) {
    __shared__ unsigned int rule[512];
    const int tid = threadIdx.x;
    int c = blockIdx.x * 512 + tid;
    float v = f0[c];
    out[c] = v;
    unsigned long long m = __ballot(v > 0.5f);
    if ((tid & 63) == 0) field[c >> 6] = m;

    if (blockIdx.x < 64) {
        {   // rule table — byte-identical math to the verified build.
            int p = tid;  // 0..511
            float logit = b2[0];
            for (int k = 0; k < hid; ++k) {
                float a = b1[k];
#pragma unroll
                for (int nn = 0; nn < 9; ++nn)
                    if (p & (1 << nn)) a += W1[nn * hid + k];
                logit += fmaxf(a, 0.0f) * W2[k];
            }
            rule[p] = (logit > 0.0f) ? 1u : 0u;
        }
        __syncthreads();
        if (tid < 128) {   // this block's 128-word slice of the quad-LUT
            int word = blockIdx.x * 128 + tid;
            unsigned int wv = 0;
#pragma unroll
            for (int k = 0; k < 8; ++k) {
                unsigned int e = (unsigned int)word * 8u + k;
                unsigned int a = e & 15u, b = (e >> 4) & 15u;
                unsigned int cc = (e >> 8) & 15u, d = (e >> 12) & 15u;
                unsigned int bit0 = rule[(a & 7u) | ((b & 7u) << 3) | ((cc & 7u) << 6)];
                unsigned int bit1 = rule[((a >> 1) & 7u) | (((b >> 1) & 7u) << 3) | (((cc >> 1) & 7u) << 6)];
                unsigned int bit2 = rule[(b & 7u) | ((cc & 7u) << 3) | ((d & 7u) << 6)];
                unsigned int bit3 = rule[((b >> 1) & 7u) | (((cc >> 1) & 7u) << 3) | (((d >> 1) & 7u) << 6)];
                wv |= (bit0 | (bit1 << 1) | (bit2 << 2) | (bit3 << 3)) << (4 * k);
            }
            lut16g[word] = wv;
        }
    }
}

// Batched quad-LUT pair evaluation: ALL 16 indices computed first (static
// unrolled array), then ALL 16 ds_reads issued, then combine — forces the
// compiler to keep ~16 LDS loads in flight instead of one serialized chain.
#define PAIR_EVAL(eA, eB, eC, eD, ow0, ow1) do {                              \
    unsigned int idxv[16];                                                    \
    _Pragma("unroll")                                                         \
    for (int j = 0; j < 16; ++j)                                              \
        idxv[j] = (unsigned int)((eA >> (2 * j)) & 15ull)                     \
                | ((unsigned int)((eB >> (2 * j)) & 15ull) << 4)              \
                | ((unsigned int)((eC >> (2 * j)) & 15ull) << 8)              \
                | ((unsigned int)((eD >> (2 * j)) & 15ull) << 12);            \
    unsigned int entv[16];                                                    \
    _Pragma("unroll")                                                         \
    for (int j = 0; j < 16; ++j)                                              \
        entv[j] = lut16[idxv[j] >> 3] >> ((idxv[j] & 7u) * 4);                \
    ow0 = 0; ow1 = 0;                                                         \
    _Pragma("unroll")                                                         \
    for (int j = 0; j < 16; ++j) {                                            \
        ow0 |= (entv[j] & 3u) << (2 * j);                                     \
        ow1 |= ((entv[j] >> 2) & 3u) << (2 * j);                              \
    }                                                                         \
} while (0)

// ---------------------------------------------------------------------------
// Kernel 2: 512 blocks (8 images x 64 row-groups) x 512 thr = 2 blocks/CU.
// Full-width tile (no column halo; wrap &15 verified R9/R12/R13). Per step:
// 4-row x 1-word STRIP tasks (two quad-LUT pairs sharing 6 window rows, 32
// independent batched lookups per thread); lgkm barrier; in-loop emit
// (R10-verified pattern). __launch_bounds__(512,2) lifts the VGPR cap.
// ---------------------------------------------------------------------------
__global__ __launch_bounds__(512, 2) void mega(const unsigned int* __restrict__ field,
                                               const unsigned int* __restrict__ lut16g,
                                               float* __restrict__ out,
                                               int n, int T) {
    __shared__ alignas(16) unsigned int lut16[8192];   // 32 KiB
    __shared__ unsigned int bufA[ROWS * WPR];
    __shared__ unsigned int bufB[ROWS * WPR];

    const int tid = threadIdx.x;
    const int rg = blockIdx.x & 63;
    const int b  = blockIdx.x >> 6;
    const int r0 = rg * RO;          // first owned global row

    for (int i = tid; i < 2048; i += 512)
        ((uint4*)lut16)[i] = ((const uint4*)lut16g)[i];
    {
        const unsigned int* F = field + b * (HH * WPR);
        for (int i = tid; i < ROWS * WPR; i += 512) {
            int l = i >> 4, w = i & 15;
            int g = (r0 - HALO + l) & (HH - 1);
            bufA[i] = F[g * WPR + w];
        }
    }
    __syncthreads();

    unsigned int* oldb = bufA;
    unsigned int* newb = bufB;
    float* outb = out + (size_t)b * (HH * WW);

    for (int t = 1; t < T; ++t) {
        const int hi = ROWS - t;                 // valid new rows [t, hi)
        const int nstrips = (hi - t + 3) >> 2;   // 4-row strips (last may be half)
        if (tid < nstrips * WPR) {
            const int st = tid >> 4;
            const int w  = tid & 15;
            const int l  = t + 4 * st;
            const int wl = (w + 15) & 15, wn = (w + 1) & 15;   // full-width wrap
            // 6 window rows (l-1 .. l+4), read-clamped to the tile (results of
            // clamped rows are discarded by the write guard below).
            unsigned long long e[6];
#pragma unroll
            for (int r = 0; r < 6; ++r) {
                int row = l - 1 + r; row = row < ROWS ? row : ROWS - 1;
                const unsigned int* R = oldb + row * WPR;
                e[r] = ((((unsigned long long)R[wn] << 32) | R[w]) << 1) | (R[wl] >> 31);
            }
            unsigned int owA0, owA1, owB0, owB1;
            PAIR_EVAL(e[0], e[1], e[2], e[3], owA0, owA1);   // rows l, l+1
            PAIR_EVAL(e[2], e[3], e[4], e[5], owB0, owB1);   // rows l+2, l+3
            newb[l * WPR + w] = owA0;
            newb[(l + 1) * WPR + w] = owA1;
            if (l + 2 < hi) {                    // second pair may be past hi
                newb[(l + 2) * WPR + w] = owB0;
                newb[(l + 3) * WPR + w] = owB1;
            }
        }
        STEP_BARRIER();    // lgkm-only: newb complete, oldb reads done;
                           // frame stores from previous steps stay in flight.

        // emit step t: owned 8 rows x 512 cols = 4096 floats, 2 passes x 512
        // float4 (R10-verified pattern); overlaps next step's compute.
        float* outt = outb + (size_t)t * n;
#pragma unroll
        for (int p = 0; p < 2; ++p) {
            int cell = (p * 512 + tid) * 4;      // 0..4092
            int lr  = cell >> 9;                 // owned row 0..7
            int col = cell & 511;                // full-width col
            unsigned int wd = newb[(HALO + lr) * WPR + (col >> 5)];
            unsigned int nib = (wd >> (col & 31)) & 15u;
            float4 v;
            v.x = (float)(nib & 1u);
            v.y = (float)((nib >> 1) & 1u);
            v.z = (float)((nib >> 2) & 1u);
            v.w = (float)(nib >> 3);
            *(float4*)(outt + (size_t)(r0 + lr) * WW + col) = v;
        }
        unsigned int* tmp = oldb; oldb = newb; newb = tmp;
    }
}

// ---------------------------------------------------------------------------
// Launch: init_pack -> mega (2 dispatches).
// d_ws: [0, 32768)            quad-LUT (8192 u32)
//       [32768, 32768 + n/8)  packed step-0 bit field (256 KiB)
// ---------------------------------------------------------------------------
extern "C" void kernel_launch(void* const* d_in, const int* in_sizes, int n_in,
                              void* d_out, int out_size, void* d_ws, size_t ws_size,
                              hipStream_t stream) {
    const float* f0 = (const float*)d_in[0];
    const float* W1 = (const float*)d_in[1];
    const float* b1 = (const float*)d_in[2];
    const float* W2 = (const float*)d_in[3];
    const float* b2 = (const float*)d_in[4];
    float* out = (float*)d_out;

    const int n = in_sizes[0];        // B*1*H*W = 2,097,152
    const int hid = in_sizes[2];      // 64
    const int T = out_size / n;       // 16
    const int B = n / (HH * WW);      // 8

    char* ws = (char*)d_ws;
    unsigned int* lut16g = (unsigned int*)ws;
    unsigned long long* fld = (unsigned long long*)(ws + 32768);

    init_pack<<<n / 512, 512, 0, stream>>>(f0, W1, b1, W2, b2, hid, out, fld, lut16g);
    mega<<<B * (HH / RO), 512, 0, stream>>>((const unsigned int*)fld, lut16g,
                                            out, n, T);
}